// Round 11
// baseline (430.026 us; speedup 1.0000x reference)
//
#include <hip/hip_runtime.h>
#include <hip/hip_bf16.h>

#define NN   50000
#define NE   640000
#define NPE  500000
#define FEPS 1e-5f

typedef __attribute__((ext_vector_type(8))) short          bf16x8;
typedef __attribute__((ext_vector_type(8))) unsigned short u16x8;
typedef __attribute__((ext_vector_type(4))) float          f32x4;

__device__ inline float b2f(unsigned short u) {
    union { unsigned int i; float f; } c; c.i = (unsigned int)u << 16; return c.f;
}
__device__ inline unsigned short f2b(float f) {
    __hip_bfloat16 h = __float2bfloat16(f);
    return *reinterpret_cast<unsigned short*>(&h);
}

// ---------------- fused init: zero cnt/cursor + all fp32->bf16 conversions ----------------
// blocks [0,98): zero 25088 int4 ; [98,3223): x ; [3223,3335): weights (contiguous dst)
__global__ __launch_bounds__(256) void k_init(
    int4* __restrict__ zdst,
    const float* __restrict__ x, unsigned short* __restrict__ xbf,
    const float* __restrict__ W1l, const float* __restrict__ W1r,
    const float* __restrict__ W2l, const float* __restrict__ W2r,
    const float* __restrict__ pW1, const float* __restrict__ pW2,
    unsigned short* __restrict__ wdst) {
    int b = blockIdx.x, t = threadIdx.x;
    if (b < 98) {
        int i = b * 256 + t;
        if (i < 25088) zdst[i] = make_int4(0, 0, 0, 0);
        return;
    }
    const float* src;
    size_t off;
    if (b < 3223) {
        int i = (b - 98) * 256 + t;
        if (i >= 800000) return;
        const float4* p = (const float4*)x + 2 * (size_t)i;
        float4 a = p[0], c = p[1];
        u16x8 o;
        o[0]=f2b(a.x); o[1]=f2b(a.y); o[2]=f2b(a.z); o[3]=f2b(a.w);
        o[4]=f2b(c.x); o[5]=f2b(c.y); o[6]=f2b(c.z); o[7]=f2b(c.w);
        *((u16x8*)xbf + i) = o;
        return;
    }
    int i = (b - 3223) * 256 + t;   // 0..28671
    if (i >= 28672) return;
    if      (i < 4096)  { src = W1l; off = i; }
    else if (i < 8192)  { src = W1r; off = i - 4096; }
    else if (i < 12288) { src = W2l; off = i - 8192; }
    else if (i < 16384) { src = W2r; off = i - 12288; }
    else if (i < 24576) { src = pW1; off = i - 16384; }
    else                { src = pW2; off = i - 24576; }
    const float4* p = (const float4*)src + 2 * off;
    float4 a = p[0], c = p[1];
    u16x8 o;
    o[0]=f2b(a.x); o[1]=f2b(a.y); o[2]=f2b(a.z); o[3]=f2b(a.w);
    o[4]=f2b(c.x); o[5]=f2b(c.y); o[6]=f2b(c.z); o[7]=f2b(c.w);
    *((u16x8*)wdst + i) = o;
}

// ---------------- CSR build ----------------
__global__ void k_hist(const int* __restrict__ key, int* __restrict__ cnt, int n) {
    int e = blockIdx.x * blockDim.x + threadIdx.x;
    if (e < n) atomicAdd(&cnt[key[e]], 1);
}

__global__ void k_scan1(const int* __restrict__ cnt, int* __restrict__ part) {
    int t = threadIdx.x, lane = t & 63, w = t >> 6;
    int i = blockIdx.x * 256 + t;
    int v = (i < NN) ? cnt[i] : 0;
#pragma unroll
    for (int d = 1; d < 64; d <<= 1) v += __shfl_xor(v, d, 64);
    __shared__ int ws[4];
    if (lane == 0) ws[w] = v;
    __syncthreads();
    if (t == 0) part[blockIdx.x] = ws[0] + ws[1] + ws[2] + ws[3];
}

// scan3 with built-in cross-block base (merged scan2+scan3)
__global__ void k_scan3(const int* __restrict__ cnt, const int* __restrict__ part,
                        int* __restrict__ rowptr) {
    int t = threadIdx.x, lane = t & 63, w = t >> 6;
    __shared__ int ws[4];
    __shared__ int sbase;
    int pvv = (t < 196 && t < blockIdx.x) ? part[t] : 0;
#pragma unroll
    for (int d = 1; d < 64; d <<= 1) pvv += __shfl_xor(pvv, d, 64);
    if (lane == 0) ws[w] = pvv;
    __syncthreads();
    if (t == 0) sbase = ws[0] + ws[1] + ws[2] + ws[3];
    __syncthreads();
    int i = blockIdx.x * 256 + t;
    int v = (i < NN) ? cnt[i] : 0;
    int s = v;
#pragma unroll
    for (int d = 1; d < 64; d <<= 1) { int u = __shfl_up(s, d, 64); if (lane >= d) s += u; }
    if (lane == 63) ws[w] = s;
    __syncthreads();
    if (t == 0) { int a = 0; for (int k = 0; k < 4; ++k) { int tmp = ws[k]; ws[k] = a; a += tmp; } }
    __syncthreads();
    if (i <= NN) rowptr[i] = sbase + ws[w] + s - v;
}

__global__ void k_fill(const int* __restrict__ src, const int* __restrict__ dst,
                       const int* __restrict__ rowptr, int* __restrict__ cursor,
                       int* __restrict__ col) {
    int e = blockIdx.x * blockDim.x + threadIdx.x;
    if (e >= NE) return;
    int d = dst[e];
    int slot = atomicAdd(&cursor[d], 1);
    col[rowptr[d] + slot] = src[e];
}

// ---------------- gather-mean (CSR), 4-phase channel-sliced for L2 residency ----------------
// phase = blockIdx.x / 12500 selects channels [p*32, p*32+32) -> 3.2 MB slice < 4 MB L2/XCD.
// Per-channel accumulation order identical to the unphased version (bit-identical output).
__global__ __launch_bounds__(256) void k_mean(const unsigned short* __restrict__ feat,
                                              const int* __restrict__ rowptr,
                                              const int* __restrict__ col,
                                              unsigned short* __restrict__ outm) {
    int phase = blockIdx.x / 12500;
    int blk   = blockIdx.x % 12500;
    int node = blk * 4 + (threadIdx.x >> 6);
    int lane = threadIdx.x & 63;
    int g = lane >> 4, li = lane & 15;
    if (node >= NN) return;
    int cbase = phase * 32 + li * 2;          // this lane's 2 channels
    const unsigned short* fp = feat + cbase;
    int beg = rowptr[node], end = rowptr[node + 1];
    float a0 = 0.f, a1 = 0.f;
    int j = beg;
    for (; j + 8 <= end; j += 8) {            // 8 neighbors in flight (2 loads/lane)
        int s0 = col[j + g], s1 = col[j + 4 + g];
        unsigned int v0 = *(const unsigned int*)(fp + (size_t)s0 * 128);
        unsigned int v1 = *(const unsigned int*)(fp + (size_t)s1 * 128);
        a0 += b2f(v0 & 0xffff) + b2f(v1 & 0xffff);
        a1 += b2f(v0 >> 16)    + b2f(v1 >> 16);
    }
    for (; j < end; j += 4) {                 // predicated tail, 4 at a time
        int idx = j + g;
        bool ok = idx < end;
        int s = ok ? col[idx] : col[beg];
        unsigned int v = *(const unsigned int*)(fp + (size_t)s * 128);
        if (ok) { a0 += b2f(v & 0xffff); a1 += b2f(v >> 16); }
    }
    a0 += __shfl_xor(a0, 16, 64); a0 += __shfl_xor(a0, 32, 64);
    a1 += __shfl_xor(a1, 16, 64); a1 += __shfl_xor(a1, 32, 64);
    if (g == 0) {
        float inv = 1.f / fmaxf((float)(end - beg), 1.f);
        unsigned int o = (unsigned int)f2b(a0 * inv) | ((unsigned int)f2b(a1 * inv) << 16);
        *(unsigned int*)(outm + (size_t)node * 128 + cbase) = o;
    }
}

// ---------------- fused SAGE1 + layer-2 linears ----------------
__global__ __launch_bounds__(256) void k_sage12(
    const unsigned short* __restrict__ mean, const unsigned short* __restrict__ self,
    const unsigned short* __restrict__ Wl, const unsigned short* __restrict__ Wr,   // [256][128]
    const float* __restrict__ b, const float* __restrict__ bg, const float* __restrict__ bb,
    const float* __restrict__ bm, const float* __restrict__ bv,
    const unsigned short* __restrict__ W2l, const unsigned short* __restrict__ W2r, // [128][256]
    const float* __restrict__ b2,
    unsigned short* __restrict__ Y, unsigned short* __restrict__ S) {
    __shared__ unsigned short AB[64 * 256];           // 32 KB: ms|xs, then reused as hs
    unsigned short* ms = AB;
    unsigned short* xs = AB + 64 * 128;
    int t = threadIdx.x;
    int n0 = blockIdx.x * 64;
    for (int j = 0; j < 4; ++j) {
        int idx = t + j * 256;
        int row = idx >> 4, c16 = idx & 15;
        int node = n0 + row;
        u16x8 v = {0,0,0,0,0,0,0,0}, v2 = {0,0,0,0,0,0,0,0};
        if (node < NN) {
            v  = *(const u16x8*)(mean + (size_t)node * 128 + c16 * 8);
            v2 = *(const u16x8*)(self + (size_t)node * 128 + c16 * 8);
        }
        int byte = row * 256 + ((c16 * 16) ^ ((row & 7) << 4));
        *(u16x8*)((char*)ms + byte) = v;
        *(u16x8*)((char*)xs + byte) = v2;
    }
    __syncthreads();
    int w = t >> 6, l = t & 63, lr = l & 15, lh = l >> 4;
    f32x4 acc[4][4];
#pragma unroll
    for (int mi = 0; mi < 4; ++mi)
#pragma unroll
        for (int ni = 0; ni < 4; ++ni) { acc[mi][ni][0]=0; acc[mi][ni][1]=0; acc[mi][ni][2]=0; acc[mi][ni][3]=0; }
#pragma unroll
    for (int half = 0; half < 2; ++half) {
        const unsigned short* A = half ? xs : ms;
        const unsigned short* W = half ? Wr : Wl;
#pragma unroll
        for (int ks = 0; ks < 4; ++ks) {
            int k0 = ks * 32;
            bf16x8 a[4], wf[4];
#pragma unroll
            for (int mi = 0; mi < 4; ++mi) {
                int row = mi * 16 + lr;
                int byte = row * 256 + ((k0 * 2 + lh * 16) ^ ((row & 7) << 4));
                a[mi] = *(const bf16x8*)((const char*)A + byte);
            }
#pragma unroll
            for (int ni = 0; ni < 4; ++ni) {
                int wrow = w * 64 + ni * 16 + lr;
                wf[ni] = *(const bf16x8*)(W + (size_t)wrow * 128 + k0 + lh * 8);
            }
#pragma unroll
            for (int mi = 0; mi < 4; ++mi)
#pragma unroll
                for (int ni = 0; ni < 4; ++ni)
                    acc[mi][ni] = __builtin_amdgcn_mfma_f32_16x16x32_bf16(a[mi], wf[ni], acc[mi][ni], 0, 0, 0);
        }
    }
    __syncthreads();   // ms/xs reads done; reuse AB as hs [64][256] (512B rows, swizzled)
#pragma unroll
    for (int ni = 0; ni < 4; ++ni) {
        int ch = w * 64 + ni * 16 + lr;
        float sc = bg[ch] * rsqrtf(bv[ch] + FEPS);
        float sh = bb[ch] - bm[ch] * sc;
        float bias = b[ch];
#pragma unroll
        for (int mi = 0; mi < 4; ++mi)
#pragma unroll
            for (int r = 0; r < 4; ++r) {
                int row = mi * 16 + lh * 4 + r;
                float vv = fmaxf((acc[mi][ni][r] + bias) * sc + sh, 0.f);
                int byte = row * 512 + ((ch * 2) ^ ((row & 7) << 4));
                *(unsigned short*)((char*)AB + byte) = f2b(vv);
            }
    }
    __syncthreads();
    f32x4 aY[4][2], aS[4][2];
#pragma unroll
    for (int mi = 0; mi < 4; ++mi)
#pragma unroll
        for (int ni = 0; ni < 2; ++ni) {
            aY[mi][ni][0]=0; aY[mi][ni][1]=0; aY[mi][ni][2]=0; aY[mi][ni][3]=0;
            aS[mi][ni][0]=0; aS[mi][ni][1]=0; aS[mi][ni][2]=0; aS[mi][ni][3]=0;
        }
#pragma unroll
    for (int ks = 0; ks < 8; ++ks) {
        int k0 = ks * 32;
        bf16x8 a[4], wl[2], wr[2];
#pragma unroll
        for (int mi = 0; mi < 4; ++mi) {
            int row = mi * 16 + lr;
            int byte = row * 512 + ((k0 * 2 + lh * 16) ^ ((row & 7) << 4));
            a[mi] = *(const bf16x8*)((const char*)AB + byte);
        }
#pragma unroll
        for (int ni = 0; ni < 2; ++ni) {
            int wrow = w * 32 + ni * 16 + lr;
            wl[ni] = *(const bf16x8*)(W2l + (size_t)wrow * 256 + k0 + lh * 8);
            wr[ni] = *(const bf16x8*)(W2r + (size_t)wrow * 256 + k0 + lh * 8);
        }
#pragma unroll
        for (int mi = 0; mi < 4; ++mi)
#pragma unroll
            for (int ni = 0; ni < 2; ++ni) {
                aY[mi][ni] = __builtin_amdgcn_mfma_f32_16x16x32_bf16(a[mi], wl[ni], aY[mi][ni], 0, 0, 0);
                aS[mi][ni] = __builtin_amdgcn_mfma_f32_16x16x32_bf16(a[mi], wr[ni], aS[mi][ni], 0, 0, 0);
            }
    }
#pragma unroll
    for (int ni = 0; ni < 2; ++ni) {
        int ch = w * 32 + ni * 16 + lr;
        float bias = b2[ch];
#pragma unroll
        for (int mi = 0; mi < 4; ++mi)
#pragma unroll
            for (int r = 0; r < 4; ++r) {
                int node = n0 + mi * 16 + lh * 4 + r;
                if (node < NN) {
                    Y[(size_t)node * 128 + ch] = f2b(aY[mi][ni][r]);
                    S[(size_t)node * 128 + ch] = f2b(aS[mi][ni][r] + bias);
                }
            }
    }
}

// ---------------- decoder precompute: z=S+mY staged ONCE; both W1-halves per block ----------------
__global__ __launch_bounds__(256) void k_prep(
    const unsigned short* __restrict__ S,      // [NN][128]
    const unsigned short* __restrict__ mY,     // [NN][128]
    const unsigned short* __restrict__ W1,     // [256][256] bf16
    const float* __restrict__ b1, const float* __restrict__ g1,
    const float* __restrict__ be1, const float* __restrict__ m1, const float* __restrict__ v1,
    unsigned short* __restrict__ Pa, unsigned short* __restrict__ Pb) {
    __shared__ unsigned short zs[64 * 128];
    int t = threadIdx.x;
    int n0 = blockIdx.x * 64;
    for (int j = 0; j < 4; ++j) {
        int idx = t + j * 256;
        int row = idx >> 4, c16 = idx & 15;
        int node = n0 + row;
        u16x8 o = {0,0,0,0,0,0,0,0};
        if (node < NN) {
            u16x8 sv = *(const u16x8*)(S  + (size_t)node * 128 + c16 * 8);
            u16x8 mv = *(const u16x8*)(mY + (size_t)node * 128 + c16 * 8);
#pragma unroll
            for (int jj = 0; jj < 8; ++jj)
                o[jj] = f2b(b2f((unsigned short)sv[jj]) + b2f((unsigned short)mv[jj]));
        }
        int byte = row * 256 + ((c16 * 16) ^ ((row & 7) << 4));
        *(u16x8*)((char*)zs + byte) = o;
    }
    __syncthreads();
    int w = t >> 6, l = t & 63, lr = l & 15, lh = l >> 4;
#pragma unroll
    for (int side = 0; side < 2; ++side) {
        f32x4 acc[4][4];
#pragma unroll
        for (int mi = 0; mi < 4; ++mi)
#pragma unroll
            for (int ni = 0; ni < 4; ++ni) { acc[mi][ni][0]=0; acc[mi][ni][1]=0; acc[mi][ni][2]=0; acc[mi][ni][3]=0; }
#pragma unroll
        for (int ks = 0; ks < 4; ++ks) {
            int k0 = ks * 32;
            bf16x8 a[4], wf[4];
#pragma unroll
            for (int mi = 0; mi < 4; ++mi) {
                int row = mi * 16 + lr;
                int byte = row * 256 + ((k0 * 2 + lh * 16) ^ ((row & 7) << 4));
                a[mi] = *(const bf16x8*)((const char*)zs + byte);
            }
#pragma unroll
            for (int ni = 0; ni < 4; ++ni) {
                int ch = w * 64 + ni * 16 + lr;
                wf[ni] = *(const bf16x8*)(W1 + (size_t)ch * 256 + side * 128 + k0 + lh * 8);
            }
#pragma unroll
            for (int mi = 0; mi < 4; ++mi)
#pragma unroll
                for (int ni = 0; ni < 4; ++ni)
                    acc[mi][ni] = __builtin_amdgcn_mfma_f32_16x16x32_bf16(a[mi], wf[ni], acc[mi][ni], 0, 0, 0);
        }
        unsigned short* P = side ? Pb : Pa;
#pragma unroll
        for (int ni = 0; ni < 4; ++ni) {
            int ch = w * 64 + ni * 16 + lr;
            float sc = g1[ch] * rsqrtf(v1[ch] + FEPS);
            float add = side ? 0.f : ((b1[ch] - m1[ch]) * sc + be1[ch]);
#pragma unroll
            for (int mi = 0; mi < 4; ++mi)
#pragma unroll
                for (int r = 0; r < 4; ++r) {
                    int node = n0 + mi * 16 + lh * 4 + r;
                    if (node < NN)
                        P[(size_t)node * 256 + ch] = f2b(acc[mi][ni][r] * sc + add);
                }
        }
    }
}

// ---------------- fused decoder (r5/r9, known-good): q1=relu(Pa[u]+Pb[v]); L2 GEMM; L3 dot ----------------
__global__ __launch_bounds__(256, 5) void k_mlp(
    const unsigned short* __restrict__ Pa, const unsigned short* __restrict__ Pb,
    const int* __restrict__ pu, const int* __restrict__ pv,
    const unsigned short* __restrict__ W2, const float* __restrict__ b2,
    const float* __restrict__ g2, const float* __restrict__ be2,
    const float* __restrict__ m2, const float* __restrict__ v2,
    const float* __restrict__ W3, const float* __restrict__ b3,
    float* __restrict__ out) {
    __shared__ unsigned short q1[64 * 256];   // 32 KB, reused for q2 after MFMA drain
    int t = threadIdx.x;
    int e0 = blockIdx.x * 64;
#pragma unroll
    for (int batch = 0; batch < 2; ++batch) {
        u16x8 A[4], B[4];
        int bofs[4];
#pragma unroll
        for (int j = 0; j < 4; ++j) {
            int idx = t + (batch * 4 + j) * 256;
            int edge = idx >> 5, c16 = idx & 31;
            int ge = e0 + edge;
            if (ge < NPE) {
                int u = pu[ge], vv = pv[ge];
                A[j] = *(const u16x8*)(Pa + (size_t)u  * 256 + c16 * 8);
                B[j] = *(const u16x8*)(Pb + (size_t)vv * 256 + c16 * 8);
            } else {
                A[j] = (u16x8){0,0,0,0,0,0,0,0};
                B[j] = (u16x8){0,0,0,0,0,0,0,0};
            }
            bofs[j] = edge * 512 + ((c16 * 16) ^ ((edge & 7) << 4));
        }
#pragma unroll
        for (int j = 0; j < 4; ++j) {
            u16x8 o;
#pragma unroll
            for (int jj = 0; jj < 8; ++jj)
                o[jj] = f2b(fmaxf(b2f((unsigned short)A[j][jj]) + b2f((unsigned short)B[j][jj]), 0.f));
            *(u16x8*)((char*)q1 + bofs[j]) = o;
        }
    }
    __syncthreads();
    int w = t >> 6, l = t & 63, lr = l & 15, lh = l >> 4;
    f32x4 acc[4][2];
#pragma unroll
    for (int mi = 0; mi < 4; ++mi)
#pragma unroll
        for (int ni = 0; ni < 2; ++ni) { acc[mi][ni][0]=0; acc[mi][ni][1]=0; acc[mi][ni][2]=0; acc[mi][ni][3]=0; }
#pragma unroll
    for (int ks = 0; ks < 8; ++ks) {
        int k0 = ks * 32;
        bf16x8 a[4], wf[2];
#pragma unroll
        for (int mi = 0; mi < 4; ++mi) {
            int row = mi * 16 + lr;
            int byte = row * 512 + ((k0 * 2 + lh * 16) ^ ((row & 7) << 4));
            a[mi] = *(const bf16x8*)((const char*)q1 + byte);
        }
#pragma unroll
        for (int ni = 0; ni < 2; ++ni) {
            int wrow = w * 32 + ni * 16 + lr;
            wf[ni] = *(const bf16x8*)(W2 + (size_t)wrow * 256 + k0 + lh * 8);
        }
#pragma unroll
        for (int mi = 0; mi < 4; ++mi)
#pragma unroll
            for (int ni = 0; ni < 2; ++ni)
                acc[mi][ni] = __builtin_amdgcn_mfma_f32_16x16x32_bf16(a[mi], wf[ni], acc[mi][ni], 0, 0, 0);
    }
    __syncthreads();   // all q1 reads done; safe to overwrite with q2
#pragma unroll
    for (int ni = 0; ni < 2; ++ni) {
        int ch = w * 32 + ni * 16 + lr;
        float sc = g2[ch] * rsqrtf(v2[ch] + FEPS);
        float sh = be2[ch] - m2[ch] * sc;
        float bias = b2[ch];
#pragma unroll
        for (int mi = 0; mi < 4; ++mi)
#pragma unroll
            for (int r = 0; r < 4; ++r) {
                int row = mi * 16 + lh * 4 + r;
                float vv = fmaxf((acc[mi][ni][r] + bias) * sc + sh, 0.f);
                int byte = row * 256 + ((ch * 2) ^ ((row & 7) << 4));
                *(unsigned short*)((char*)q1 + byte) = f2b(vv);
            }
    }
    __syncthreads();
    {   // layer 3: [64x128] @ W3(128); 4 threads per edge
        int edge = t >> 2, part = t & 3;
        float p = 0.f;
#pragma unroll
        for (int s = 0; s < 4; ++s) {
            int byte = edge * 256 + ((part * 64 + s * 16) ^ ((edge & 7) << 4));
            u16x8 v = *(const u16x8*)((const char*)q1 + byte);
#pragma unroll
            for (int jj = 0; jj < 8; ++jj)
                p += b2f((unsigned short)v[jj]) * W3[part * 32 + s * 8 + jj];
        }
        p += __shfl_xor(p, 1, 64);
        p += __shfl_xor(p, 2, 64);
        int ge = e0 + edge;
        if (part == 0 && ge < NPE) out[ge] = p + b3[0];
    }
}

extern "C" void kernel_launch(void* const* d_in, const int* in_sizes, int n_in,
                              void* d_out, int out_size, void* d_ws, size_t ws_size,
                              hipStream_t stream) {
    const float* x    = (const float*)d_in[0];
    const int*   ei   = (const int*)d_in[1];
    const int*   pei  = (const int*)d_in[2];
    const float* W1l  = (const float*)d_in[3];
    const float* W1r  = (const float*)d_in[4];
    const float* b1   = (const float*)d_in[5];
    const float* bn1g = (const float*)d_in[6];
    const float* bn1b = (const float*)d_in[7];
    const float* bn1m = (const float*)d_in[8];
    const float* bn1v = (const float*)d_in[9];
    const float* W2l  = (const float*)d_in[10];
    const float* W2r  = (const float*)d_in[11];
    const float* b2   = (const float*)d_in[12];
    const float* pW1  = (const float*)d_in[13];
    const float* pb1  = (const float*)d_in[14];
    const float* pg1  = (const float*)d_in[15];
    const float* pbb1 = (const float*)d_in[16];
    const float* pm1  = (const float*)d_in[17];
    const float* pv1  = (const float*)d_in[18];
    const float* pW2  = (const float*)d_in[19];
    const float* pb2  = (const float*)d_in[20];
    const float* pg2  = (const float*)d_in[21];
    const float* pbb2 = (const float*)d_in[22];
    const float* pm2  = (const float*)d_in[23];
    const float* pv2  = (const float*)d_in[24];
    const float* pW3  = (const float*)d_in[25];
    const float* pb3  = (const float*)d_in[26];
    float* out = (float*)d_out;

    const int* src = ei;
    const int* dst = ei + NE;
    const int* pu  = pei;
    const int* pv  = pei + NPE;

    char* p = (char*)d_ws;
    auto alloc = [&](size_t bytes) -> char* {
        char* r = p; p += (bytes + 255) & ~(size_t)255; return r;
    };
    int* cnt     = (int*)alloc((size_t)NN * 4);          // zeroed by k_init (with cursor)
    int* cursor  = (int*)alloc((size_t)NN * 4);
    int* part    = (int*)alloc(256 * 4);
    int* rowptr  = (int*)alloc((size_t)(NN + 1) * 4);
    int* col     = (int*)alloc((size_t)NE * 4);
    unsigned short* xbf  = (unsigned short*)alloc((size_t)NN * 128 * 2);  // -> Pb lower half
    unsigned short* mx   = (unsigned short*)alloc((size_t)NN * 128 * 2);  // -> Pb upper half
    unsigned short* Ybf  = (unsigned short*)alloc((size_t)NN * 128 * 2);
    unsigned short* mY   = (unsigned short*)alloc((size_t)NN * 128 * 2);
    unsigned short* Sbf  = (unsigned short*)alloc((size_t)NN * 128 * 2);
    unsigned short* Pa   = (unsigned short*)alloc((size_t)NN * 256 * 2);
    unsigned short* W1lb = (unsigned short*)alloc((size_t)256 * 128 * 2); // contiguous weight block
    unsigned short* W1rb = (unsigned short*)alloc((size_t)256 * 128 * 2);
    unsigned short* W2lb = (unsigned short*)alloc((size_t)128 * 256 * 2);
    unsigned short* W2rb = (unsigned short*)alloc((size_t)128 * 256 * 2);
    unsigned short* pW1b = (unsigned short*)alloc((size_t)256 * 256 * 2);
    unsigned short* pW2b = (unsigned short*)alloc((size_t)128 * 256 * 2);
    unsigned short* Pb = xbf;   // [NN][256] spanning xbf+mx (dead after k_sage12)

    // 1. fused zero (cnt,cursor) + bf16 conversions
    k_init<<<3335, 256, 0, stream>>>((int4*)cnt, x, xbf,
                                     W1l, W1r, W2l, W2r, pW1, pW2, W1lb);
    // CSR build (aggregation, keyed by dst)
    k_hist<<<2500, 256, 0, stream>>>(dst, cnt, NE);
    k_scan1<<<196, 256, 0, stream>>>(cnt, part);
    k_scan3<<<196, 256, 0, stream>>>(cnt, part, rowptr);
    k_fill<<<2500, 256, 0, stream>>>(src, dst, rowptr, cursor, col);

    // encoder (phase-major means: 4 x 12500 blocks)
    k_mean<<<50000, 256, 0, stream>>>(xbf, rowptr, col, mx);
    k_sage12<<<782, 256, 0, stream>>>(mx, xbf, W1lb, W1rb, b1, bn1g, bn1b, bn1m, bn1v,
                                      W2lb, W2rb, b2, Ybf, Sbf);
    k_mean<<<50000, 256, 0, stream>>>(Ybf, rowptr, col, mY);

    // decoder precompute (Pb overwrites xbf+mx — dead now)
    k_prep<<<782, 256, 0, stream>>>(Sbf, mY, pW1b, pb1, pg1, pbb1, pm1, pv1, Pa, Pb);

    // fused decoder
    k_mlp<<<(NPE + 63) / 64, 256, 0, stream>>>(Pa, Pb, pu, pv,
                                               pW2b, pb2, pg2, pbb2, pm2, pv2,
                                               pW3, pb3, out);
}

// Round 12
// 341.642 us; speedup vs baseline: 1.2587x; 1.2587x over previous
//
#include <hip/hip_runtime.h>
#include <hip/hip_bf16.h>

#define NN   50000
#define NE   640000
#define NPE  500000
#define FEPS 1e-5f

typedef __attribute__((ext_vector_type(8))) short          bf16x8;
typedef __attribute__((ext_vector_type(8))) unsigned short u16x8;
typedef __attribute__((ext_vector_type(4))) float          f32x4;

__device__ inline float b2f(unsigned short u) {
    union { unsigned int i; float f; } c; c.i = (unsigned int)u << 16; return c.f;
}
__device__ inline unsigned short f2b(float f) {
    __hip_bfloat16 h = __float2bfloat16(f);
    return *reinterpret_cast<unsigned short*>(&h);
}

// ---------------- fused init: zero cnt/cursor + all fp32->bf16 conversions ----------------
// blocks [0,98): zero 25088 int4 ; [98,3223): x ; [3223,3335): weights (contiguous dst)
__global__ __launch_bounds__(256) void k_init(
    int4* __restrict__ zdst,
    const float* __restrict__ x, unsigned short* __restrict__ xbf,
    const float* __restrict__ W1l, const float* __restrict__ W1r,
    const float* __restrict__ W2l, const float* __restrict__ W2r,
    const float* __restrict__ pW1, const float* __restrict__ pW2,
    unsigned short* __restrict__ wdst) {
    int b = blockIdx.x, t = threadIdx.x;
    if (b < 98) {
        int i = b * 256 + t;
        if (i < 25088) zdst[i] = make_int4(0, 0, 0, 0);
        return;
    }
    const float* src;
    size_t off;
    if (b < 3223) {
        int i = (b - 98) * 256 + t;
        if (i >= 800000) return;
        const float4* p = (const float4*)x + 2 * (size_t)i;
        float4 a = p[0], c = p[1];
        u16x8 o;
        o[0]=f2b(a.x); o[1]=f2b(a.y); o[2]=f2b(a.z); o[3]=f2b(a.w);
        o[4]=f2b(c.x); o[5]=f2b(c.y); o[6]=f2b(c.z); o[7]=f2b(c.w);
        *((u16x8*)xbf + i) = o;
        return;
    }
    int i = (b - 3223) * 256 + t;   // 0..28671
    if (i >= 28672) return;
    if      (i < 4096)  { src = W1l; off = i; }
    else if (i < 8192)  { src = W1r; off = i - 4096; }
    else if (i < 12288) { src = W2l; off = i - 8192; }
    else if (i < 16384) { src = W2r; off = i - 12288; }
    else if (i < 24576) { src = pW1; off = i - 16384; }
    else                { src = pW2; off = i - 24576; }
    const float4* p = (const float4*)src + 2 * off;
    float4 a = p[0], c = p[1];
    u16x8 o;
    o[0]=f2b(a.x); o[1]=f2b(a.y); o[2]=f2b(a.z); o[3]=f2b(a.w);
    o[4]=f2b(c.x); o[5]=f2b(c.y); o[6]=f2b(c.z); o[7]=f2b(c.w);
    *((u16x8*)wdst + i) = o;
}

// ---------------- CSR build ----------------
__global__ void k_hist(const int* __restrict__ key, int* __restrict__ cnt, int n) {
    int e = blockIdx.x * blockDim.x + threadIdx.x;
    if (e < n) atomicAdd(&cnt[key[e]], 1);
}

__global__ void k_scan1(const int* __restrict__ cnt, int* __restrict__ part) {
    int t = threadIdx.x, lane = t & 63, w = t >> 6;
    int i = blockIdx.x * 256 + t;
    int v = (i < NN) ? cnt[i] : 0;
#pragma unroll
    for (int d = 1; d < 64; d <<= 1) v += __shfl_xor(v, d, 64);
    __shared__ int ws[4];
    if (lane == 0) ws[w] = v;
    __syncthreads();
    if (t == 0) part[blockIdx.x] = ws[0] + ws[1] + ws[2] + ws[3];
}

// scan3 with built-in cross-block base (merged scan2+scan3)
__global__ void k_scan3(const int* __restrict__ cnt, const int* __restrict__ part,
                        int* __restrict__ rowptr) {
    int t = threadIdx.x, lane = t & 63, w = t >> 6;
    __shared__ int ws[4];
    __shared__ int sbase;
    int pvv = (t < 196 && t < blockIdx.x) ? part[t] : 0;
#pragma unroll
    for (int d = 1; d < 64; d <<= 1) pvv += __shfl_xor(pvv, d, 64);
    if (lane == 0) ws[w] = pvv;
    __syncthreads();
    if (t == 0) sbase = ws[0] + ws[1] + ws[2] + ws[3];
    __syncthreads();
    int i = blockIdx.x * 256 + t;
    int v = (i < NN) ? cnt[i] : 0;
    int s = v;
#pragma unroll
    for (int d = 1; d < 64; d <<= 1) { int u = __shfl_up(s, d, 64); if (lane >= d) s += u; }
    if (lane == 63) ws[w] = s;
    __syncthreads();
    if (t == 0) { int a = 0; for (int k = 0; k < 4; ++k) { int tmp = ws[k]; ws[k] = a; a += tmp; } }
    __syncthreads();
    if (i <= NN) rowptr[i] = sbase + ws[w] + s - v;
}

__global__ void k_fill(const int* __restrict__ src, const int* __restrict__ dst,
                       const int* __restrict__ rowptr, int* __restrict__ cursor,
                       int* __restrict__ col) {
    int e = blockIdx.x * blockDim.x + threadIdx.x;
    if (e >= NE) return;
    int d = dst[e];
    int slot = atomicAdd(&cursor[d], 1);
    col[rowptr[d] + slot] = src[e];
}

// ---------------- gather-mean (CSR), 16B/lane, single-flight 16-neighbor predicated ----------------
// wave = 1 node; lane-group g (16 lanes) handles neighbors j+g, j+g+4, j+g+8, j+g+12 in ONE flight.
// P(deg<=16)~84% -> ~1.2 memory round trips per node (r9 form needed ~2.3).
__global__ __launch_bounds__(256) void k_mean(const unsigned short* __restrict__ feat,
                                              const int* __restrict__ rowptr,
                                              const int* __restrict__ col,
                                              unsigned short* __restrict__ outm) {
    int node = blockIdx.x * 4 + (threadIdx.x >> 6);
    int lane = threadIdx.x & 63;
    int g = lane >> 4, li = lane & 15;
    if (node >= NN) return;
    int beg = rowptr[node], end = rowptr[node + 1];
    float acc[8];
#pragma unroll
    for (int k = 0; k < 8; ++k) acc[k] = 0.f;
    int sdum = (beg < end) ? col[beg] : 0;   // dummy row for predicated-off slots (broadcast, cheap)
    for (int j = beg; j < end; j += 16) {
        int i0 = j + g, i1 = i0 + 4, i2 = i0 + 8, i3 = i0 + 12;
        bool k0 = i0 < end, k1 = i1 < end, k2 = i2 < end, k3 = i3 < end;
        int s0 = k0 ? col[i0] : sdum;
        int s1 = k1 ? col[i1] : sdum;
        int s2 = k2 ? col[i2] : sdum;
        int s3 = k3 ? col[i3] : sdum;
        u16x8 v0 = *(const u16x8*)(feat + (size_t)s0 * 128 + li * 8);
        u16x8 v1 = *(const u16x8*)(feat + (size_t)s1 * 128 + li * 8);
        u16x8 v2 = *(const u16x8*)(feat + (size_t)s2 * 128 + li * 8);
        u16x8 v3 = *(const u16x8*)(feat + (size_t)s3 * 128 + li * 8);
#pragma unroll
        for (int k = 0; k < 8; ++k) {
            float t = 0.f;
            if (k0) t += b2f((unsigned short)v0[k]);
            if (k1) t += b2f((unsigned short)v1[k]);
            if (k2) t += b2f((unsigned short)v2[k]);
            if (k3) t += b2f((unsigned short)v3[k]);
            acc[k] += t;
        }
    }
#pragma unroll
    for (int k = 0; k < 8; ++k) {
        acc[k] += __shfl_xor(acc[k], 16, 64);
        acc[k] += __shfl_xor(acc[k], 32, 64);
    }
    if (g == 0) {
        float inv = 1.f / fmaxf((float)(end - beg), 1.f);
        u16x8 o;
#pragma unroll
        for (int k = 0; k < 8; ++k) o[k] = f2b(acc[k] * inv);
        *(u16x8*)(outm + (size_t)node * 128 + li * 8) = o;
    }
}

// ---------------- fused SAGE1 + layer-2 linears ----------------
__global__ __launch_bounds__(256) void k_sage12(
    const unsigned short* __restrict__ mean, const unsigned short* __restrict__ self,
    const unsigned short* __restrict__ Wl, const unsigned short* __restrict__ Wr,   // [256][128]
    const float* __restrict__ b, const float* __restrict__ bg, const float* __restrict__ bb,
    const float* __restrict__ bm, const float* __restrict__ bv,
    const unsigned short* __restrict__ W2l, const unsigned short* __restrict__ W2r, // [128][256]
    const float* __restrict__ b2,
    unsigned short* __restrict__ Y, unsigned short* __restrict__ S) {
    __shared__ unsigned short AB[64 * 256];           // 32 KB: ms|xs, then reused as hs
    unsigned short* ms = AB;
    unsigned short* xs = AB + 64 * 128;
    int t = threadIdx.x;
    int n0 = blockIdx.x * 64;
    for (int j = 0; j < 4; ++j) {
        int idx = t + j * 256;
        int row = idx >> 4, c16 = idx & 15;
        int node = n0 + row;
        u16x8 v = {0,0,0,0,0,0,0,0}, v2 = {0,0,0,0,0,0,0,0};
        if (node < NN) {
            v  = *(const u16x8*)(mean + (size_t)node * 128 + c16 * 8);
            v2 = *(const u16x8*)(self + (size_t)node * 128 + c16 * 8);
        }
        int byte = row * 256 + ((c16 * 16) ^ ((row & 7) << 4));
        *(u16x8*)((char*)ms + byte) = v;
        *(u16x8*)((char*)xs + byte) = v2;
    }
    __syncthreads();
    int w = t >> 6, l = t & 63, lr = l & 15, lh = l >> 4;
    f32x4 acc[4][4];
#pragma unroll
    for (int mi = 0; mi < 4; ++mi)
#pragma unroll
        for (int ni = 0; ni < 4; ++ni) { acc[mi][ni][0]=0; acc[mi][ni][1]=0; acc[mi][ni][2]=0; acc[mi][ni][3]=0; }
#pragma unroll
    for (int half = 0; half < 2; ++half) {
        const unsigned short* A = half ? xs : ms;
        const unsigned short* W = half ? Wr : Wl;
#pragma unroll
        for (int ks = 0; ks < 4; ++ks) {
            int k0 = ks * 32;
            bf16x8 a[4], wf[4];
#pragma unroll
            for (int mi = 0; mi < 4; ++mi) {
                int row = mi * 16 + lr;
                int byte = row * 256 + ((k0 * 2 + lh * 16) ^ ((row & 7) << 4));
                a[mi] = *(const bf16x8*)((const char*)A + byte);
            }
#pragma unroll
            for (int ni = 0; ni < 4; ++ni) {
                int wrow = w * 64 + ni * 16 + lr;
                wf[ni] = *(const bf16x8*)(W + (size_t)wrow * 128 + k0 + lh * 8);
            }
#pragma unroll
            for (int mi = 0; mi < 4; ++mi)
#pragma unroll
                for (int ni = 0; ni < 4; ++ni)
                    acc[mi][ni] = __builtin_amdgcn_mfma_f32_16x16x32_bf16(a[mi], wf[ni], acc[mi][ni], 0, 0, 0);
        }
    }
    __syncthreads();   // ms/xs reads done; reuse AB as hs [64][256] (512B rows, swizzled)
#pragma unroll
    for (int ni = 0; ni < 4; ++ni) {
        int ch = w * 64 + ni * 16 + lr;
        float sc = bg[ch] * rsqrtf(bv[ch] + FEPS);
        float sh = bb[ch] - bm[ch] * sc;
        float bias = b[ch];
#pragma unroll
        for (int mi = 0; mi < 4; ++mi)
#pragma unroll
            for (int r = 0; r < 4; ++r) {
                int row = mi * 16 + lh * 4 + r;
                float vv = fmaxf((acc[mi][ni][r] + bias) * sc + sh, 0.f);
                int byte = row * 512 + ((ch * 2) ^ ((row & 7) << 4));
                *(unsigned short*)((char*)AB + byte) = f2b(vv);
            }
    }
    __syncthreads();
    f32x4 aY[4][2], aS[4][2];
#pragma unroll
    for (int mi = 0; mi < 4; ++mi)
#pragma unroll
        for (int ni = 0; ni < 2; ++ni) {
            aY[mi][ni][0]=0; aY[mi][ni][1]=0; aY[mi][ni][2]=0; aY[mi][ni][3]=0;
            aS[mi][ni][0]=0; aS[mi][ni][1]=0; aS[mi][ni][2]=0; aS[mi][ni][3]=0;
        }
#pragma unroll
    for (int ks = 0; ks < 8; ++ks) {
        int k0 = ks * 32;
        bf16x8 a[4], wl[2], wr[2];
#pragma unroll
        for (int mi = 0; mi < 4; ++mi) {
            int row = mi * 16 + lr;
            int byte = row * 512 + ((k0 * 2 + lh * 16) ^ ((row & 7) << 4));
            a[mi] = *(const bf16x8*)((const char*)AB + byte);
        }
#pragma unroll
        for (int ni = 0; ni < 2; ++ni) {
            int wrow = w * 32 + ni * 16 + lr;
            wl[ni] = *(const bf16x8*)(W2l + (size_t)wrow * 256 + k0 + lh * 8);
            wr[ni] = *(const bf16x8*)(W2r + (size_t)wrow * 256 + k0 + lh * 8);
        }
#pragma unroll
        for (int mi = 0; mi < 4; ++mi)
#pragma unroll
            for (int ni = 0; ni < 2; ++ni) {
                aY[mi][ni] = __builtin_amdgcn_mfma_f32_16x16x32_bf16(a[mi], wl[ni], aY[mi][ni], 0, 0, 0);
                aS[mi][ni] = __builtin_amdgcn_mfma_f32_16x16x32_bf16(a[mi], wr[ni], aS[mi][ni], 0, 0, 0);
            }
    }
#pragma unroll
    for (int ni = 0; ni < 2; ++ni) {
        int ch = w * 32 + ni * 16 + lr;
        float bias = b2[ch];
#pragma unroll
        for (int mi = 0; mi < 4; ++mi)
#pragma unroll
            for (int r = 0; r < 4; ++r) {
                int node = n0 + mi * 16 + lh * 4 + r;
                if (node < NN) {
                    Y[(size_t)node * 128 + ch] = f2b(aY[mi][ni][r]);
                    S[(size_t)node * 128 + ch] = f2b(aS[mi][ni][r] + bias);
                }
            }
    }
}

// ---------------- decoder precompute: z=S+mY staged ONCE; both W1-halves per block ----------------
__global__ __launch_bounds__(256) void k_prep(
    const unsigned short* __restrict__ S,      // [NN][128]
    const unsigned short* __restrict__ mY,     // [NN][128]
    const unsigned short* __restrict__ W1,     // [256][256] bf16
    const float* __restrict__ b1, const float* __restrict__ g1,
    const float* __restrict__ be1, const float* __restrict__ m1, const float* __restrict__ v1,
    unsigned short* __restrict__ Pa, unsigned short* __restrict__ Pb) {
    __shared__ unsigned short zs[64 * 128];
    int t = threadIdx.x;
    int n0 = blockIdx.x * 64;
    for (int j = 0; j < 4; ++j) {
        int idx = t + j * 256;
        int row = idx >> 4, c16 = idx & 15;
        int node = n0 + row;
        u16x8 o = {0,0,0,0,0,0,0,0};
        if (node < NN) {
            u16x8 sv = *(const u16x8*)(S  + (size_t)node * 128 + c16 * 8);
            u16x8 mv = *(const u16x8*)(mY + (size_t)node * 128 + c16 * 8);
#pragma unroll
            for (int jj = 0; jj < 8; ++jj)
                o[jj] = f2b(b2f((unsigned short)sv[jj]) + b2f((unsigned short)mv[jj]));
        }
        int byte = row * 256 + ((c16 * 16) ^ ((row & 7) << 4));
        *(u16x8*)((char*)zs + byte) = o;
    }
    __syncthreads();
    int w = t >> 6, l = t & 63, lr = l & 15, lh = l >> 4;
#pragma unroll
    for (int side = 0; side < 2; ++side) {
        f32x4 acc[4][4];
#pragma unroll
        for (int mi = 0; mi < 4; ++mi)
#pragma unroll
            for (int ni = 0; ni < 4; ++ni) { acc[mi][ni][0]=0; acc[mi][ni][1]=0; acc[mi][ni][2]=0; acc[mi][ni][3]=0; }
#pragma unroll
        for (int ks = 0; ks < 4; ++ks) {
            int k0 = ks * 32;
            bf16x8 a[4], wf[4];
#pragma unroll
            for (int mi = 0; mi < 4; ++mi) {
                int row = mi * 16 + lr;
                int byte = row * 256 + ((k0 * 2 + lh * 16) ^ ((row & 7) << 4));
                a[mi] = *(const bf16x8*)((const char*)zs + byte);
            }
#pragma unroll
            for (int ni = 0; ni < 4; ++ni) {
                int ch = w * 64 + ni * 16 + lr;
                wf[ni] = *(const bf16x8*)(W1 + (size_t)ch * 256 + side * 128 + k0 + lh * 8);
            }
#pragma unroll
            for (int mi = 0; mi < 4; ++mi)
#pragma unroll
                for (int ni = 0; ni < 4; ++ni)
                    acc[mi][ni] = __builtin_amdgcn_mfma_f32_16x16x32_bf16(a[mi], wf[ni], acc[mi][ni], 0, 0, 0);
        }
        unsigned short* P = side ? Pb : Pa;
#pragma unroll
        for (int ni = 0; ni < 4; ++ni) {
            int ch = w * 64 + ni * 16 + lr;
            float sc = g1[ch] * rsqrtf(v1[ch] + FEPS);
            float add = side ? 0.f : ((b1[ch] - m1[ch]) * sc + be1[ch]);
#pragma unroll
            for (int mi = 0; mi < 4; ++mi)
#pragma unroll
                for (int r = 0; r < 4; ++r) {
                    int node = n0 + mi * 16 + lh * 4 + r;
                    if (node < NN)
                        P[(size_t)node * 256 + ch] = f2b(acc[mi][ni][r] * sc + add);
                }
        }
    }
}

// ---------------- fused decoder (r5/r9, known-good): q1=relu(Pa[u]+Pb[v]); L2 GEMM; L3 dot ----------------
__global__ __launch_bounds__(256, 5) void k_mlp(
    const unsigned short* __restrict__ Pa, const unsigned short* __restrict__ Pb,
    const int* __restrict__ pu, const int* __restrict__ pv,
    const unsigned short* __restrict__ W2, const float* __restrict__ b2,
    const float* __restrict__ g2, const float* __restrict__ be2,
    const float* __restrict__ m2, const float* __restrict__ v2,
    const float* __restrict__ W3, const float* __restrict__ b3,
    float* __restrict__ out) {
    __shared__ unsigned short q1[64 * 256];   // 32 KB, reused for q2 after MFMA drain
    int t = threadIdx.x;
    int e0 = blockIdx.x * 64;
#pragma unroll
    for (int batch = 0; batch < 2; ++batch) {
        u16x8 A[4], B[4];
        int bofs[4];
#pragma unroll
        for (int j = 0; j < 4; ++j) {
            int idx = t + (batch * 4 + j) * 256;
            int edge = idx >> 5, c16 = idx & 31;
            int ge = e0 + edge;
            if (ge < NPE) {
                int u = pu[ge], vv = pv[ge];
                A[j] = *(const u16x8*)(Pa + (size_t)u  * 256 + c16 * 8);
                B[j] = *(const u16x8*)(Pb + (size_t)vv * 256 + c16 * 8);
            } else {
                A[j] = (u16x8){0,0,0,0,0,0,0,0};
                B[j] = (u16x8){0,0,0,0,0,0,0,0};
            }
            bofs[j] = edge * 512 + ((c16 * 16) ^ ((edge & 7) << 4));
        }
#pragma unroll
        for (int j = 0; j < 4; ++j) {
            u16x8 o;
#pragma unroll
            for (int jj = 0; jj < 8; ++jj)
                o[jj] = f2b(fmaxf(b2f((unsigned short)A[j][jj]) + b2f((unsigned short)B[j][jj]), 0.f));
            *(u16x8*)((char*)q1 + bofs[j]) = o;
        }
    }
    __syncthreads();
    int w = t >> 6, l = t & 63, lr = l & 15, lh = l >> 4;
    f32x4 acc[4][2];
#pragma unroll
    for (int mi = 0; mi < 4; ++mi)
#pragma unroll
        for (int ni = 0; ni < 2; ++ni) { acc[mi][ni][0]=0; acc[mi][ni][1]=0; acc[mi][ni][2]=0; acc[mi][ni][3]=0; }
#pragma unroll
    for (int ks = 0; ks < 8; ++ks) {
        int k0 = ks * 32;
        bf16x8 a[4], wf[2];
#pragma unroll
        for (int mi = 0; mi < 4; ++mi) {
            int row = mi * 16 + lr;
            int byte = row * 512 + ((k0 * 2 + lh * 16) ^ ((row & 7) << 4));
            a[mi] = *(const bf16x8*)((const char*)q1 + byte);
        }
#pragma unroll
        for (int ni = 0; ni < 2; ++ni) {
            int wrow = w * 32 + ni * 16 + lr;
            wf[ni] = *(const bf16x8*)(W2 + (size_t)wrow * 256 + k0 + lh * 8);
        }
#pragma unroll
        for (int mi = 0; mi < 4; ++mi)
#pragma unroll
            for (int ni = 0; ni < 2; ++ni)
                acc[mi][ni] = __builtin_amdgcn_mfma_f32_16x16x32_bf16(a[mi], wf[ni], acc[mi][ni], 0, 0, 0);
    }
    __syncthreads();   // all q1 reads done; safe to overwrite with q2
#pragma unroll
    for (int ni = 0; ni < 2; ++ni) {
        int ch = w * 32 + ni * 16 + lr;
        float sc = g2[ch] * rsqrtf(v2[ch] + FEPS);
        float sh = be2[ch] - m2[ch] * sc;
        float bias = b2[ch];
#pragma unroll
        for (int mi = 0; mi < 4; ++mi)
#pragma unroll
            for (int r = 0; r < 4; ++r) {
                int row = mi * 16 + lh * 4 + r;
                float vv = fmaxf((acc[mi][ni][r] + bias) * sc + sh, 0.f);
                int byte = row * 256 + ((ch * 2) ^ ((row & 7) << 4));
                *(unsigned short*)((char*)q1 + byte) = f2b(vv);
            }
    }
    __syncthreads();
    {   // layer 3: [64x128] @ W3(128); 4 threads per edge
        int edge = t >> 2, part = t & 3;
        float p = 0.f;
#pragma unroll
        for (int s = 0; s < 4; ++s) {
            int byte = edge * 256 + ((part * 64 + s * 16) ^ ((edge & 7) << 4));
            u16x8 v = *(const u16x8*)((const char*)q1 + byte);
#pragma unroll
            for (int jj = 0; jj < 8; ++jj)
                p += b2f((unsigned short)v[jj]) * W3[part * 32 + s * 8 + jj];
        }
        p += __shfl_xor(p, 1, 64);
        p += __shfl_xor(p, 2, 64);
        int ge = e0 + edge;
        if (part == 0 && ge < NPE) out[ge] = p + b3[0];
    }
}

extern "C" void kernel_launch(void* const* d_in, const int* in_sizes, int n_in,
                              void* d_out, int out_size, void* d_ws, size_t ws_size,
                              hipStream_t stream) {
    const float* x    = (const float*)d_in[0];
    const int*   ei   = (const int*)d_in[1];
    const int*   pei  = (const int*)d_in[2];
    const float* W1l  = (const float*)d_in[3];
    const float* W1r  = (const float*)d_in[4];
    const float* b1   = (const float*)d_in[5];
    const float* bn1g = (const float*)d_in[6];
    const float* bn1b = (const float*)d_in[7];
    const float* bn1m = (const float*)d_in[8];
    const float* bn1v = (const float*)d_in[9];
    const float* W2l  = (const float*)d_in[10];
    const float* W2r  = (const float*)d_in[11];
    const float* b2   = (const float*)d_in[12];
    const float* pW1  = (const float*)d_in[13];
    const float* pb1  = (const float*)d_in[14];
    const float* pg1  = (const float*)d_in[15];
    const float* pbb1 = (const float*)d_in[16];
    const float* pm1  = (const float*)d_in[17];
    const float* pv1  = (const float*)d_in[18];
    const float* pW2  = (const float*)d_in[19];
    const float* pb2  = (const float*)d_in[20];
    const float* pg2  = (const float*)d_in[21];
    const float* pbb2 = (const float*)d_in[22];
    const float* pm2  = (const float*)d_in[23];
    const float* pv2  = (const float*)d_in[24];
    const float* pW3  = (const float*)d_in[25];
    const float* pb3  = (const float*)d_in[26];
    float* out = (float*)d_out;

    const int* src = ei;
    const int* dst = ei + NE;
    const int* pu  = pei;
    const int* pv  = pei + NPE;

    char* p = (char*)d_ws;
    auto alloc = [&](size_t bytes) -> char* {
        char* r = p; p += (bytes + 255) & ~(size_t)255; return r;
    };
    int* cnt     = (int*)alloc((size_t)NN * 4);          // zeroed by k_init (with cursor)
    int* cursor  = (int*)alloc((size_t)NN * 4);
    int* part    = (int*)alloc(256 * 4);
    int* rowptr  = (int*)alloc((size_t)(NN + 1) * 4);
    int* col     = (int*)alloc((size_t)NE * 4);
    unsigned short* xbf  = (unsigned short*)alloc((size_t)NN * 128 * 2);  // -> Pb lower half
    unsigned short* mx   = (unsigned short*)alloc((size_t)NN * 128 * 2);  // -> Pb upper half
    unsigned short* Ybf  = (unsigned short*)alloc((size_t)NN * 128 * 2);
    unsigned short* mY   = (unsigned short*)alloc((size_t)NN * 128 * 2);
    unsigned short* Sbf  = (unsigned short*)alloc((size_t)NN * 128 * 2);
    unsigned short* Pa   = (unsigned short*)alloc((size_t)NN * 256 * 2);
    unsigned short* W1lb = (unsigned short*)alloc((size_t)256 * 128 * 2); // contiguous weight block
    unsigned short* W1rb = (unsigned short*)alloc((size_t)256 * 128 * 2);
    unsigned short* W2lb = (unsigned short*)alloc((size_t)128 * 256 * 2);
    unsigned short* W2rb = (unsigned short*)alloc((size_t)128 * 256 * 2);
    unsigned short* pW1b = (unsigned short*)alloc((size_t)256 * 256 * 2);
    unsigned short* pW2b = (unsigned short*)alloc((size_t)128 * 256 * 2);
    unsigned short* Pb = xbf;   // [NN][256] spanning xbf+mx (dead after k_sage12)

    // 1. fused zero (cnt,cursor) + bf16 conversions
    k_init<<<3335, 256, 0, stream>>>((int4*)cnt, x, xbf,
                                     W1l, W1r, W2l, W2r, pW1, pW2, W1lb);
    // CSR build (aggregation, keyed by dst)
    k_hist<<<2500, 256, 0, stream>>>(dst, cnt, NE);
    k_scan1<<<196, 256, 0, stream>>>(cnt, part);
    k_scan3<<<196, 256, 0, stream>>>(cnt, part, rowptr);
    k_fill<<<2500, 256, 0, stream>>>(src, dst, rowptr, cursor, col);

    // encoder
    k_mean<<<12500, 256, 0, stream>>>(xbf, rowptr, col, mx);
    k_sage12<<<782, 256, 0, stream>>>(mx, xbf, W1lb, W1rb, b1, bn1g, bn1b, bn1m, bn1v,
                                      W2lb, W2rb, b2, Ybf, Sbf);
    k_mean<<<12500, 256, 0, stream>>>(Ybf, rowptr, col, mY);

    // decoder precompute (Pb overwrites xbf+mx — dead now)
    k_prep<<<782, 256, 0, stream>>>(Sbf, mY, pW1b, pb1, pg1, pbb1, pm1, pv1, Pa, Pb);

    // fused decoder
    k_mlp<<<(NPE + 63) / 64, 256, 0, stream>>>(Pa, Pb, pu, pv,
                                               pW2b, pb2, pg2, pbb2, pm2, pv2,
                                               pW3, pb3, out);
}